// Round 2
// baseline (1055.574 us; speedup 1.0000x reference)
//
#include <hip/hip_runtime.h>
#include <hip/hip_bf16.h>
#include <math.h>

typedef unsigned short u16;
typedef __attribute__((ext_vector_type(4))) float f32x4;
typedef __attribute__((ext_vector_type(8))) short bf16x8;

#define GLD16(gptr, lptr) __builtin_amdgcn_global_load_lds( \
    (const __attribute__((address_space(1))) void*)(gptr),  \
    (__attribute__((address_space(3))) void*)(lptr), 16, 0, 0)

__device__ __forceinline__ float bf2f(u16 u) {
  union { unsigned int i; float f; } c; c.i = ((unsigned int)u) << 16; return c.f;
}
__device__ __forceinline__ u16 f2bf(float f) {
  union { float f; unsigned int i; } c; c.f = f;
  unsigned int r = c.i + 0x7fffu + ((c.i >> 16) & 1u);
  return (u16)(r >> 16);
}

// ---------------- fp32 -> bf16 elementwise (float4 vectorized) ----------------
__global__ __launch_bounds__(256) void f32_to_bf16(const float* __restrict__ in,
                                                   u16* __restrict__ out, int n4) {
  int i = blockIdx.x * 256 + threadIdx.x;
  if (i >= n4) return;
  float4 v = reinterpret_cast<const float4*>(in)[i];
  ushort4 o;
  o.x = f2bf(v.x); o.y = f2bf(v.y); o.z = f2bf(v.z); o.w = f2bf(v.w);
  reinterpret_cast<ushort4*>(out)[i] = o;
}

// ---------------- W[K][N] fp32 -> Wt[N][K] bf16 (tiled transpose) ----------------
__global__ __launch_bounds__(256) void transpose_convert(const float* __restrict__ W,
                                                         u16* __restrict__ Wt,
                                                         int K, int N) {
  __shared__ float tile[32][33];
  const int n0 = blockIdx.x * 32, k0 = blockIdx.y * 32;
  const int tx = threadIdx.x & 31, ty = threadIdx.x >> 5;
#pragma unroll
  for (int r = 0; r < 32; r += 8)
    tile[ty + r][tx] = W[(size_t)(k0 + ty + r) * N + (n0 + tx)];
  __syncthreads();
#pragma unroll
  for (int r = 0; r < 32; r += 8)
    Wt[(size_t)(n0 + ty + r) * K + (k0 + tx)] = f2bf(tile[tx][ty + r]);
}

// ---------------- V[2048][1024] bf16 -> Vt[8][128][2048] bf16 ----------------
__global__ __launch_bounds__(256) void transpose_v(const u16* __restrict__ V,
                                                   u16* __restrict__ Vt) {
  __shared__ u16 tile[32][33];
  const int t0 = blockIdx.x * 32, d0 = blockIdx.y * 32, hkv = blockIdx.z;
  const int tx = threadIdx.x & 31, ty = threadIdx.x >> 5;
#pragma unroll
  for (int r = 0; r < 32; r += 8)
    tile[ty + r][tx] = V[(size_t)(t0 + ty + r) * 1024 + hkv * 128 + d0 + tx];
  __syncthreads();
#pragma unroll
  for (int r = 0; r < 32; r += 8)
    Vt[((size_t)hkv * 128 + d0 + ty + r) * 2048 + t0 + tx] = tile[tx][ty + r];
}

// ---------------- RoPE in-place on bf16 [T][nheads*128] ----------------
__global__ __launch_bounds__(256) void rope_kernel(u16* __restrict__ X, int nheads,
                                                   const int* __restrict__ pos_ptr) {
  int idx = blockIdx.x * 256 + threadIdx.x;
  int total = 2048 * nheads * 64;
  if (idx >= total) return;
  int d = idx & 63;
  int h = (idx >> 6) % nheads;
  int t = idx / (64 * nheads);
  int pos = *pos_ptr;
  float inv = powf(500000.0f, -(float)d * (1.0f / 64.0f));
  float ang = (float)(pos + t) * inv;
  float c = cosf(ang), s = sinf(ang);
  size_t base = (size_t)t * nheads * 128 + h * 128 + d;
  float x1 = bf2f(X[base]);
  float x2 = bf2f(X[base + 64]);
  X[base]      = f2bf(x1 * c - x2 * s);
  X[base + 64] = f2bf(x2 * c + x1 * s);
}

// ---------------- bf16 GEMM: C[M][N] = A[M][K] @ Bt[N][K]^T ----------------
template <int OUT_BF16>
__global__ __launch_bounds__(256) void gemm_bt(const u16* __restrict__ A,
                                               const u16* __restrict__ Bt,
                                               void* __restrict__ C,
                                               int M, int N, int K) {
  __shared__ alignas(16) u16 As[128 * 32];
  __shared__ alignas(16) u16 Bs[128 * 32];
  const int tid = threadIdx.x;
  const int w = tid >> 6, lane = tid & 63;
  const int l15 = lane & 15, lg = lane >> 4;
  const int wr = w >> 1, wc = w & 1;
  const int m0 = blockIdx.y * 128, n0 = blockIdx.x * 128;
  const int srow = lane >> 2;
  const int scol = (lane & 3) * 8;

  f32x4 acc[4][4];
#pragma unroll
  for (int i = 0; i < 4; ++i)
#pragma unroll
    for (int j = 0; j < 4; ++j) {
      f32x4 z = {0.f, 0.f, 0.f, 0.f};
      acc[i][j] = z;
    }

  for (int k0 = 0; k0 < K; k0 += 32) {
#pragma unroll
    for (int p = 0; p < 2; ++p) {
      const int rbase = w * 32 + p * 16;
      GLD16(A  + (size_t)(m0 + rbase + srow) * K + k0 + scol, &As[rbase * 32]);
      GLD16(Bt + (size_t)(n0 + rbase + srow) * K + k0 + scol, &Bs[rbase * 32]);
    }
    __syncthreads();
    bf16x8 af[4], bfr[4];
#pragma unroll
    for (int i = 0; i < 4; ++i)
      af[i] = *reinterpret_cast<const bf16x8*>(&As[(wr * 64 + i * 16 + l15) * 32 + lg * 8]);
#pragma unroll
    for (int j = 0; j < 4; ++j)
      bfr[j] = *reinterpret_cast<const bf16x8*>(&Bs[(wc * 64 + j * 16 + l15) * 32 + lg * 8]);
#pragma unroll
    for (int i = 0; i < 4; ++i)
#pragma unroll
      for (int j = 0; j < 4; ++j)
        acc[i][j] = __builtin_amdgcn_mfma_f32_16x16x32_bf16(af[i], bfr[j], acc[i][j], 0, 0, 0);
    __syncthreads();
  }

#pragma unroll
  for (int i = 0; i < 4; ++i)
#pragma unroll
    for (int j = 0; j < 4; ++j)
#pragma unroll
      for (int r = 0; r < 4; ++r) {
        const int row = m0 + wr * 64 + i * 16 + lg * 4 + r;
        const int col = n0 + wc * 64 + j * 16 + l15;
        const float v = acc[i][j][r];
        if (OUT_BF16) ((u16*)C)[(size_t)row * N + col] = f2bf(v);
        else          ((float*)C)[(size_t)row * N + col] = v;
      }
}

// ---------------- GQA causal flash attention, LDS-free K/V ----------------
// grid (32, 32) = (q-blocks reversed, heads). 4 independent waves/block,
// each owns 16 q-rows. KV step 64. No __syncthreads anywhere.
__global__ __launch_bounds__(256) void attn_kernel(const u16* __restrict__ Q,
                                                   const u16* __restrict__ K,
                                                   const u16* __restrict__ Vt,
                                                   u16* __restrict__ O,
                                                   const int* __restrict__ pos_ptr) {
  const int pos = *pos_ptr;
  const int h = blockIdx.y;
  const int hkv = h >> 2;
  const int tid = threadIdx.x;
  const int w = tid >> 6, lane = tid & 63;
  const int l15 = lane & 15, lg = lane >> 4;

  __shared__ alignas(16) u16 Pl[4][16][72];   // per-wave P staging, 16B-aligned rows

  const int qb = (int)gridDim.x - 1 - (int)blockIdx.x;  // heavy blocks first
  const int qt0 = qb * 64;

  const u16* Kh = K + hkv * 128;
  const u16* Vh = Vt + (size_t)hkv * 128 * 2048;

  const int qrow_frag = qt0 + w * 16 + l15;
  bf16x8 qa[4];
#pragma unroll
  for (int kk = 0; kk < 4; ++kk)
    qa[kk] = *reinterpret_cast<const bf16x8*>(Q + (size_t)qrow_frag * 4096 + h * 128 + kk * 32 + lg * 8);

  f32x4 acc[8];
#pragma unroll
  for (int i = 0; i < 8; ++i) { f32x4 z = {0.f, 0.f, 0.f, 0.f}; acc[i] = z; }
  float mrun[4], lrun[4];
#pragma unroll
  for (int r = 0; r < 4; ++r) {
    mrun[r] = (pos > 0) ? 0.0f : -INFINITY;  // zero-key prefix: logit 0 x pos
    lrun[r] = (float)pos;
  }

  const int qrow_c = qt0 + w * 16 + lg * 4;
  const int nst = qb + 1;
  const float scale = 0.08838834764831845f;  // 1/sqrt(128)

  for (int st = 0; st < nst; ++st) {
    const int s0 = st * 64;

    // ---- QK^T: four 16x16 s-subtiles, B-fragments direct from global K ----
    float pv[4][4];
#pragma unroll
    for (int sub = 0; sub < 4; ++sub) {
      f32x4 s4 = {0.f, 0.f, 0.f, 0.f};
      const u16* kp = Kh + (size_t)(s0 + sub * 16 + l15) * 1024 + lg * 8;
#pragma unroll
      for (int kk = 0; kk < 4; ++kk) {
        bf16x8 kf = *reinterpret_cast<const bf16x8*>(kp + kk * 32);
        s4 = __builtin_amdgcn_mfma_f32_16x16x32_bf16(qa[kk], kf, s4, 0, 0, 0);
      }
#pragma unroll
      for (int r = 0; r < 4; ++r) pv[sub][r] = s4[r];
    }

    // ---- online softmax (mask only on the diagonal tile) ----
    const bool lastt = (st == nst - 1);
    float sf[4];
#pragma unroll
    for (int r = 0; r < 4; ++r) {
      const int qrow = qrow_c + r;
      float mx = -INFINITY;
#pragma unroll
      for (int sub = 0; sub < 4; ++sub) {
        float v = pv[sub][r] * scale;
        if (lastt) {
          const int scol = s0 + sub * 16 + l15;
          v = (scol <= qrow) ? v : -INFINITY;
        }
        pv[sub][r] = v;
        mx = fmaxf(mx, v);
      }
#pragma unroll
      for (int off = 1; off < 16; off <<= 1) mx = fmaxf(mx, __shfl_xor(mx, off));
      const float mnew = fmaxf(mrun[r], mx);
      const float scf = __expf(mrun[r] - mnew);
      sf[r] = scf;
      float psum = 0.0f;
#pragma unroll
      for (int sub = 0; sub < 4; ++sub) {
        const float p = __expf(pv[sub][r] - mnew);
        pv[sub][r] = p;
        psum += p;
      }
#pragma unroll
      for (int off = 1; off < 16; off <<= 1) psum += __shfl_xor(psum, off);
      lrun[r] = lrun[r] * scf + psum;
      mrun[r] = mnew;
    }
#pragma unroll
    for (int dc = 0; dc < 8; ++dc)
#pragma unroll
      for (int r = 0; r < 4; ++r) acc[dc][r] *= sf[r];

    // ---- P -> per-wave LDS (no barrier: wave-local write->read) ----
#pragma unroll
    for (int sub = 0; sub < 4; ++sub)
#pragma unroll
      for (int r = 0; r < 4; ++r)
        Pl[w][lg * 4 + r][sub * 16 + l15] = f2bf(pv[sub][r]);

    // ---- PV: acc[16q][128d] += P[16][64] @ V[64][128], V^T direct from global ----
#pragma unroll
    for (int ks = 0; ks < 2; ++ks) {
      bf16x8 pf = *reinterpret_cast<const bf16x8*>(&Pl[w][l15][ks * 32 + lg * 8]);
      const u16* vp = Vh + (size_t)l15 * 2048 + s0 + ks * 32 + lg * 8;
#pragma unroll
      for (int dc = 0; dc < 8; ++dc) {
        bf16x8 vf = *reinterpret_cast<const bf16x8*>(vp + (size_t)dc * 16 * 2048);
        acc[dc] = __builtin_amdgcn_mfma_f32_16x16x32_bf16(pf, vf, acc[dc], 0, 0, 0);
      }
    }
  }

#pragma unroll
  for (int dc = 0; dc < 8; ++dc)
#pragma unroll
    for (int r = 0; r < 4; ++r) {
      const int qrow = qrow_c + r;
      O[(size_t)qrow * 4096 + h * 128 + dc * 16 + l15] = f2bf(acc[dc][r] / lrun[r]);
    }
}

extern "C" void kernel_launch(void* const* d_in, const int* in_sizes, int n_in,
                              void* d_out, int out_size, void* d_ws, size_t ws_size,
                              hipStream_t stream) {
  const float* hs = (const float*)d_in[0];
  const float* Wq = (const float*)d_in[1];
  const float* Wk = (const float*)d_in[2];
  const float* Wv = (const float*)d_in[3];
  const float* Wo = (const float*)d_in[4];
  const int* pos  = (const int*)d_in[5];

  char* ws = (char*)d_ws;
  // layout (bytes), peak 92,274,688:
  u16* Qb    = (u16*)(ws + 0);           // 2048*4096 bf16 (16 MB)
  u16* Kb    = (u16*)(ws + 16777216ULL); // 2048*1024 (4 MB)
  u16* Vb    = (u16*)(ws + 20971520ULL); // 2048*1024 (4 MB)
  u16* WqT   = (u16*)(ws + 25165824ULL); // 4096*4096 (32 MB)
  u16* attn  = WqT;                      // [2048][4096] (16 MB) after Q-GEMM done
  u16* Vtg   = (u16*)(ws + 41943040ULL); // [8][128][2048] (4 MB), upper WqT half
  u16* hs_bf = (u16*)(ws + 58720256ULL); // 2048*4096 (16 MB)
  u16* WkT   = (u16*)(ws + 75497472ULL); // 1024*4096 (8 MB)
  u16* WvT   = (u16*)(ws + 83886080ULL); // 1024*4096 (8 MB)
  u16* WoT   = (u16*)(ws + 58720256ULL); // aliases hs_bf+WkT+WvT after QKV GEMMs

  f32_to_bf16<<<8192, 256, 0, stream>>>(hs, hs_bf, 2097152);
  transpose_convert<<<dim3(128, 128), 256, 0, stream>>>(Wq, WqT, 4096, 4096);
  transpose_convert<<<dim3(32, 128), 256, 0, stream>>>(Wk, WkT, 4096, 1024);
  transpose_convert<<<dim3(32, 128), 256, 0, stream>>>(Wv, WvT, 4096, 1024);

  gemm_bt<1><<<dim3(32, 16), 256, 0, stream>>>(hs_bf, WqT, Qb, 2048, 4096, 4096);
  gemm_bt<1><<<dim3(8, 16), 256, 0, stream>>>(hs_bf, WkT, Kb, 2048, 1024, 4096);
  gemm_bt<1><<<dim3(8, 16), 256, 0, stream>>>(hs_bf, WvT, Vb, 2048, 1024, 4096);

  // Wo transpose AFTER QKV GEMMs: WoT overwrites hs_bf/WkT/WvT (now dead)
  transpose_convert<<<dim3(128, 128), 256, 0, stream>>>(Wo, WoT, 4096, 4096);

  rope_kernel<<<16384, 256, 0, stream>>>(Qb, 32, pos);
  rope_kernel<<<4096, 256, 0, stream>>>(Kb, 8, pos);

  // V -> Vt[hkv][d][t]; overwrites upper half of WqT (dead after Q-GEMM)
  transpose_v<<<dim3(64, 4, 8), 256, 0, stream>>>(Vb, Vtg);

  attn_kernel<<<dim3(32, 32), 256, 0, stream>>>(Qb, Kb, Vtg, attn, pos);

  gemm_bt<0><<<dim3(32, 16), 256, 0, stream>>>(attn, WoT, d_out, 2048, 4096, 4096);
}

// Round 3
// 540.166 us; speedup vs baseline: 1.9542x; 1.9542x over previous
//
#include <hip/hip_runtime.h>
#include <hip/hip_bf16.h>
#include <math.h>

typedef unsigned short u16;
typedef __attribute__((ext_vector_type(4))) float f32x4;
typedef __attribute__((ext_vector_type(8))) short bf16x8;

#define GLD16(gptr, lptr) __builtin_amdgcn_global_load_lds( \
    (const __attribute__((address_space(1))) void*)(gptr),  \
    (__attribute__((address_space(3))) void*)(lptr), 16, 0, 0)

__device__ __forceinline__ float bf2f(u16 u) {
  union { unsigned int i; float f; } c; c.i = ((unsigned int)u) << 16; return c.f;
}
__device__ __forceinline__ u16 f2bf(float f) {
  union { float f; unsigned int i; } c; c.f = f;
  unsigned int r = c.i + 0x7fffu + ((c.i >> 16) & 1u);
  return (u16)(r >> 16);
}

// ---------------- fp32 -> bf16 elementwise (float4 vectorized) ----------------
__global__ __launch_bounds__(256) void f32_to_bf16(const float* __restrict__ in,
                                                   u16* __restrict__ out, int n4) {
  int i = blockIdx.x * 256 + threadIdx.x;
  if (i >= n4) return;
  float4 v = reinterpret_cast<const float4*>(in)[i];
  ushort4 o;
  o.x = f2bf(v.x); o.y = f2bf(v.y); o.z = f2bf(v.z); o.w = f2bf(v.w);
  reinterpret_cast<ushort4*>(out)[i] = o;
}

// ---------------- W[K][N] fp32 -> Wt[N][K] bf16 (tiled transpose) ----------------
__global__ __launch_bounds__(256) void transpose_convert(const float* __restrict__ W,
                                                         u16* __restrict__ Wt,
                                                         int K, int N) {
  __shared__ float tile[32][33];
  const int n0 = blockIdx.x * 32, k0 = blockIdx.y * 32;
  const int tx = threadIdx.x & 31, ty = threadIdx.x >> 5;
#pragma unroll
  for (int r = 0; r < 32; r += 8)
    tile[ty + r][tx] = W[(size_t)(k0 + ty + r) * N + (n0 + tx)];
  __syncthreads();
#pragma unroll
  for (int r = 0; r < 32; r += 8)
    Wt[(size_t)(n0 + ty + r) * K + (k0 + tx)] = f2bf(tile[tx][ty + r]);
}

// ------- V half of KV[2048][2048] -> Vt[8][128][2048] bf16 (d-major) -------
__global__ __launch_bounds__(256) void transpose_v(const u16* __restrict__ KV,
                                                   u16* __restrict__ Vt) {
  __shared__ u16 tile[32][33];
  const int t0 = blockIdx.x * 32, d0 = blockIdx.y * 32, hkv = blockIdx.z;
  const int tx = threadIdx.x & 31, ty = threadIdx.x >> 5;
#pragma unroll
  for (int r = 0; r < 32; r += 8)
    tile[ty + r][tx] = KV[(size_t)(t0 + ty + r) * 2048 + 1024 + hkv * 128 + d0 + tx];
  __syncthreads();
#pragma unroll
  for (int r = 0; r < 32; r += 8)
    Vt[((size_t)hkv * 128 + d0 + ty + r) * 2048 + t0 + tx] = tile[tx][ty + r];
}

// ---------------- RoPE cos/sin table: tab[t][d] for t<2048, d<64 ----------------
__global__ __launch_bounds__(256) void rope_table(float2* __restrict__ tab,
                                                  const int* __restrict__ pos_ptr) {
  int idx = blockIdx.x * 256 + threadIdx.x;  // 131072
  int d = idx & 63, t = idx >> 6;
  int pos = *pos_ptr;
  // 500000^(-d/64) = exp2(-d/64 * log2(500000))
  float inv = exp2f(-(float)d * (0.015625f * 18.931568569324174f));
  float ang = (float)(pos + t) * inv;
  tab[idx] = make_float2(cosf(ang), sinf(ang));
}

// ---------------- RoPE apply in-place on bf16 [T][stride] ----------------
__global__ __launch_bounds__(256) void rope_apply(u16* __restrict__ X, int nheads,
                                                  int stride,
                                                  const float2* __restrict__ tab) {
  int idx = blockIdx.x * 256 + threadIdx.x;
  int total = 2048 * nheads * 64;
  if (idx >= total) return;
  int d = idx & 63;
  int h = (idx >> 6) % nheads;
  int t = idx / (64 * nheads);
  float2 cs = tab[t * 64 + d];
  size_t base = (size_t)t * stride + h * 128 + d;
  float x1 = bf2f(X[base]);
  float x2 = bf2f(X[base + 64]);
  X[base]      = f2bf(x1 * cs.x - x2 * cs.y);
  X[base + 64] = f2bf(x2 * cs.x + x1 * cs.y);
}

// ---------------- bf16 GEMM: C[M][N] = A[M][K] @ Bt[N][K]^T ----------------
template <int OUT_BF16>
__global__ __launch_bounds__(256) void gemm_bt(const u16* __restrict__ A,
                                               const u16* __restrict__ Bt,
                                               void* __restrict__ C,
                                               int M, int N, int K) {
  __shared__ alignas(16) u16 As[128 * 32];
  __shared__ alignas(16) u16 Bs[128 * 32];
  const int tid = threadIdx.x;
  const int w = tid >> 6, lane = tid & 63;
  const int l15 = lane & 15, lg = lane >> 4;
  const int wr = w >> 1, wc = w & 1;
  const int m0 = blockIdx.y * 128, n0 = blockIdx.x * 128;
  const int srow = lane >> 2;
  const int scol = (lane & 3) * 8;

  f32x4 acc[4][4];
#pragma unroll
  for (int i = 0; i < 4; ++i)
#pragma unroll
    for (int j = 0; j < 4; ++j) {
      f32x4 z = {0.f, 0.f, 0.f, 0.f};
      acc[i][j] = z;
    }

  for (int k0 = 0; k0 < K; k0 += 32) {
#pragma unroll
    for (int p = 0; p < 2; ++p) {
      const int rbase = w * 32 + p * 16;
      GLD16(A  + (size_t)(m0 + rbase + srow) * K + k0 + scol, &As[rbase * 32]);
      GLD16(Bt + (size_t)(n0 + rbase + srow) * K + k0 + scol, &Bs[rbase * 32]);
    }
    __syncthreads();
    bf16x8 af[4], bfr[4];
#pragma unroll
    for (int i = 0; i < 4; ++i)
      af[i] = *reinterpret_cast<const bf16x8*>(&As[(wr * 64 + i * 16 + l15) * 32 + lg * 8]);
#pragma unroll
    for (int j = 0; j < 4; ++j)
      bfr[j] = *reinterpret_cast<const bf16x8*>(&Bs[(wc * 64 + j * 16 + l15) * 32 + lg * 8]);
#pragma unroll
    for (int i = 0; i < 4; ++i)
#pragma unroll
      for (int j = 0; j < 4; ++j)
        acc[i][j] = __builtin_amdgcn_mfma_f32_16x16x32_bf16(af[i], bfr[j], acc[i][j], 0, 0, 0);
    __syncthreads();
  }

#pragma unroll
  for (int i = 0; i < 4; ++i)
#pragma unroll
    for (int j = 0; j < 4; ++j)
#pragma unroll
      for (int r = 0; r < 4; ++r) {
        const int row = m0 + wr * 64 + i * 16 + lg * 4 + r;
        const int col = n0 + wc * 64 + j * 16 + l15;
        const float v = acc[i][j][r];
        if (OUT_BF16) ((u16*)C)[(size_t)row * N + col] = f2bf(v);
        else          ((float*)C)[(size_t)row * N + col] = v;
      }
}

// ---------------- GQA causal flash attention ----------------
// grid (32, 32) = (q-blocks reversed, heads). 4 waves, each owns 16 q-rows.
// KVBLK=64, double-buffered LDS, XOR-swizzled (16B chunk ^ row&7), 1 barrier/tile.
__global__ __launch_bounds__(256) void attn_kernel(const u16* __restrict__ Q,
                                                   const u16* __restrict__ KV,
                                                   const u16* __restrict__ Vt,
                                                   u16* __restrict__ O,
                                                   const int* __restrict__ pos_ptr) {
  const int pos = *pos_ptr;
  const int h = blockIdx.y;
  const int hkv = h >> 2;
  const int tid = threadIdx.x;
  const int w = tid >> 6, lane = tid & 63;
  const int l15 = lane & 15, lg = lane >> 4;

  // K tile [64][128]: 16 chunks/row; V tile [128][64]: 8 chunks/row. 16B chunks.
  __shared__ alignas(16) u16 Ks[2][64 * 128];
  __shared__ alignas(16) u16 Vs[2][128 * 64];
  __shared__ alignas(16) u16 Pl[4][16][72];

  const int qb = (int)gridDim.x - 1 - (int)blockIdx.x;  // heavy blocks first
  const int qt0 = qb * 64;
  const int nst = qb + 1;

  const u16* Kh = KV + hkv * 128;                        // row stride 2048
  const u16* Vh = Vt + (size_t)hkv * 128 * 2048;         // row stride 2048

  const int qrow_frag = qt0 + w * 16 + l15;
  bf16x8 qa[4];
#pragma unroll
  for (int kk = 0; kk < 4; ++kk)
    qa[kk] = *reinterpret_cast<const bf16x8*>(Q + (size_t)qrow_frag * 4096 + h * 128 + kk * 32 + lg * 8);

  f32x4 acc[8];
#pragma unroll
  for (int i = 0; i < 8; ++i) { f32x4 z = {0.f, 0.f, 0.f, 0.f}; acc[i] = z; }
  float mrun[4], lrun[4];
#pragma unroll
  for (int r = 0; r < 4; ++r) {
    mrun[r] = (pos > 0) ? 0.0f : -INFINITY;  // zero-key prefix: logit 0 x pos
    lrun[r] = (float)pos;
  }

  const int qrow_c = qt0 + w * 16 + lg * 4;
  const float scale = 0.08838834764831845f;  // 1/sqrt(128)
  const int wvb = tid & ~63;  // wave-uniform thread base

  // stage tile st into buffer b: linear LDS dest, inverse-swizzled global source
#define STAGE_TILE(st_, b_)                                                        \
  do {                                                                             \
    const int s0_ = (st_) * 64;                                                    \
    _Pragma("unroll")                                                              \
    for (int p = 0; p < 4; ++p) {                                                  \
      const int idx = p * 256 + tid;                                               \
      const int kr = idx >> 4, kc = (idx & 15) ^ (kr & 7);                         \
      GLD16(Kh + (size_t)(s0_ + kr) * 2048 + kc * 8, &Ks[b_][(p * 256 + wvb) * 8]);\
      const int vr = idx >> 3, vc = (idx & 7) ^ (vr & 7);                          \
      GLD16(Vh + (size_t)vr * 2048 + s0_ + vc * 8, &Vs[b_][(p * 256 + wvb) * 8]);  \
    }                                                                              \
  } while (0)

  STAGE_TILE(0, 0);
  __syncthreads();
  int cur = 0;

  for (int st = 0; st < nst; ++st) {
    if (st + 1 < nst) STAGE_TILE(st + 1, cur ^ 1);
    const int s0 = st * 64;

    // ---- QK^T: four 16x16 s-subtiles from swizzled K LDS ----
    float pv[4][4];
    __builtin_amdgcn_s_setprio(1);
#pragma unroll
    for (int sub = 0; sub < 4; ++sub) {
      f32x4 s4 = {0.f, 0.f, 0.f, 0.f};
      const int row = sub * 16 + l15;
#pragma unroll
      for (int kk = 0; kk < 4; ++kk) {
        const int chunk = (kk * 4 + lg) ^ (row & 7);
        bf16x8 kf = *reinterpret_cast<const bf16x8*>(&Ks[cur][row * 128 + chunk * 8]);
        s4 = __builtin_amdgcn_mfma_f32_16x16x32_bf16(qa[kk], kf, s4, 0, 0, 0);
      }
#pragma unroll
      for (int r = 0; r < 4; ++r) pv[sub][r] = s4[r];
    }
    __builtin_amdgcn_s_setprio(0);

    // ---- online softmax (mask only on the diagonal tile) ----
    const bool lastt = (st == nst - 1);
    float sf[4];
#pragma unroll
    for (int r = 0; r < 4; ++r) {
      const int qrow = qrow_c + r;
      float mx = -INFINITY;
#pragma unroll
      for (int sub = 0; sub < 4; ++sub) {
        float v = pv[sub][r] * scale;
        if (lastt) {
          const int scol = s0 + sub * 16 + l15;
          v = (scol <= qrow) ? v : -INFINITY;
        }
        pv[sub][r] = v;
        mx = fmaxf(mx, v);
      }
#pragma unroll
      for (int off = 1; off < 16; off <<= 1) mx = fmaxf(mx, __shfl_xor(mx, off));
      const float mnew = fmaxf(mrun[r], mx);
      const float scf = __expf(mrun[r] - mnew);
      sf[r] = scf;
      float psum = 0.0f;
#pragma unroll
      for (int sub = 0; sub < 4; ++sub) {
        const float p = __expf(pv[sub][r] - mnew);
        pv[sub][r] = p;
        psum += p;
      }
#pragma unroll
      for (int off = 1; off < 16; off <<= 1) psum += __shfl_xor(psum, off);
      lrun[r] = lrun[r] * scf + psum;
      mrun[r] = mnew;
    }
#pragma unroll
    for (int dc = 0; dc < 8; ++dc)
#pragma unroll
      for (int r = 0; r < 4; ++r) acc[dc][r] *= sf[r];

    // ---- P -> per-wave LDS (wave-local, no barrier) ----
#pragma unroll
    for (int sub = 0; sub < 4; ++sub)
#pragma unroll
      for (int r = 0; r < 4; ++r)
        Pl[w][lg * 4 + r][sub * 16 + l15] = f2bf(pv[sub][r]);

    // ---- PV: acc[16q][128d] += P[16][64] @ V[64][128] from swizzled V LDS ----
    __builtin_amdgcn_s_setprio(1);
#pragma unroll
    for (int ks = 0; ks < 2; ++ks) {
      bf16x8 pf = *reinterpret_cast<const bf16x8*>(&Pl[w][l15][ks * 32 + lg * 8]);
#pragma unroll
      for (int dc = 0; dc < 8; ++dc) {
        const int row = dc * 16 + l15;
        const int chunk = (ks * 4 + lg) ^ (row & 7);
        bf16x8 vf = *reinterpret_cast<const bf16x8*>(&Vs[cur][row * 64 + chunk * 8]);
        acc[dc] = __builtin_amdgcn_mfma_f32_16x16x32_bf16(pf, vf, acc[dc], 0, 0, 0);
      }
    }
    __builtin_amdgcn_s_setprio(0);

    __syncthreads();  // drains vmcnt (next tile staged) + protects buffer swap
    cur ^= 1;
  }
#undef STAGE_TILE

#pragma unroll
  for (int dc = 0; dc < 8; ++dc)
#pragma unroll
    for (int r = 0; r < 4; ++r) {
      const int qrow = qrow_c + r;
      O[(size_t)qrow * 4096 + h * 128 + dc * 16 + l15] = f2bf(acc[dc][r] / lrun[r]);
    }
}

extern "C" void kernel_launch(void* const* d_in, const int* in_sizes, int n_in,
                              void* d_out, int out_size, void* d_ws, size_t ws_size,
                              hipStream_t stream) {
  const float* hs = (const float*)d_in[0];
  const float* Wq = (const float*)d_in[1];
  const float* Wk = (const float*)d_in[2];
  const float* Wv = (const float*)d_in[3];
  const float* Wo = (const float*)d_in[4];
  const int* pos  = (const int*)d_in[5];

  char* ws = (char*)d_ws;
  // layout (bytes), peak 92,274,688:
  u16* Qb    = (u16*)(ws + 0);           // [2048][4096] bf16 (16 MB)
  u16* KVb   = (u16*)(ws + 16777216ULL); // [2048][2048] bf16 (8 MB): cols 0..1023=K, 1024..2047=V
  u16* WqT   = (u16*)(ws + 25165824ULL); // [4096][4096] (32 MB)
  u16* attn  = WqT;                      // [2048][4096] (16 MB), after Q-GEMM done
  u16* Vtg   = (u16*)(ws + 41943040ULL); // [8][128][2048] (4 MB), inside dead WqT
  float2* tabF = (float2*)(ws + 46137344ULL); // [2048][64] float2 (1 MB), inside dead WqT
  u16* hs_bf = (u16*)(ws + 58720256ULL); // [2048][4096] (16 MB)
  u16* WkT   = (u16*)(ws + 75497472ULL); // [1024][4096] (8 MB)  } contiguous ->
  u16* WvT   = (u16*)(ws + 83886080ULL); // [1024][4096] (8 MB)  } combined Bt[2048][4096]
  u16* WoT   = (u16*)(ws + 58720256ULL); // aliases hs_bf+WkT+WvT after QKV GEMMs

  f32_to_bf16<<<8192, 256, 0, stream>>>(hs, hs_bf, 2097152);
  transpose_convert<<<dim3(128, 128), 256, 0, stream>>>(Wq, WqT, 4096, 4096);
  transpose_convert<<<dim3(32, 128), 256, 0, stream>>>(Wk, WkT, 4096, 1024);
  transpose_convert<<<dim3(32, 128), 256, 0, stream>>>(Wv, WvT, 4096, 1024);

  gemm_bt<1><<<dim3(32, 16), 256, 0, stream>>>(hs_bf, WqT, Qb, 2048, 4096, 4096);
  // combined K+V projection: Bt = [WkT ; WvT] (contiguous), C = KVb [2048][2048]
  gemm_bt<1><<<dim3(16, 16), 256, 0, stream>>>(hs_bf, WkT, KVb, 2048, 2048, 4096);

  // Wo transpose AFTER GEMMs: WoT overwrites hs_bf/WkT/WvT (now dead)
  transpose_convert<<<dim3(128, 128), 256, 0, stream>>>(Wo, WoT, 4096, 4096);

  rope_table<<<512, 256, 0, stream>>>(tabF, pos);
  rope_apply<<<16384, 256, 0, stream>>>(Qb, 32, 4096, tabF);
  rope_apply<<<4096, 256, 0, stream>>>(KVb, 8, 2048, tabF);

  // V half of KVb -> Vt[hkv][d][t]
  transpose_v<<<dim3(64, 4, 8), 256, 0, stream>>>(KVb, Vtg);

  attn_kernel<<<dim3(32, 32), 256, 0, stream>>>(Qb, KVb, Vtg, attn, pos);

  gemm_bt<0><<<dim3(32, 16), 256, 0, stream>>>(attn, WoT, d_out, 2048, 4096, 4096);
}

// Round 5
// 474.975 us; speedup vs baseline: 2.2224x; 1.1373x over previous
//
#include <hip/hip_runtime.h>
#include <hip/hip_bf16.h>
#include <math.h>

typedef unsigned short u16;
typedef __attribute__((ext_vector_type(4))) float f32x4;
typedef __attribute__((ext_vector_type(8))) short bf16x8;

#define GLD16(gptr, lptr) __builtin_amdgcn_global_load_lds( \
    (const __attribute__((address_space(1))) void*)(gptr),  \
    (__attribute__((address_space(3))) void*)(lptr), 16, 0, 0)

__device__ __forceinline__ float bf2f(u16 u) {
  union { unsigned int i; float f; } c; c.i = ((unsigned int)u) << 16; return c.f;
}
__device__ __forceinline__ u16 f2bf(float f) {
  union { float f; unsigned int i; } c; c.f = f;
  unsigned int r = c.i + 0x7fffu + ((c.i >> 16) & 1u);
  return (u16)(r >> 16);
}

// ---------------- fp32 -> bf16 elementwise (float4 vectorized) ----------------
__global__ __launch_bounds__(256) void f32_to_bf16(const float* __restrict__ in,
                                                   u16* __restrict__ out, int n4) {
  int i = blockIdx.x * 256 + threadIdx.x;
  if (i >= n4) return;
  float4 v = reinterpret_cast<const float4*>(in)[i];
  ushort4 o;
  o.x = f2bf(v.x); o.y = f2bf(v.y); o.z = f2bf(v.z); o.w = f2bf(v.w);
  reinterpret_cast<ushort4*>(out)[i] = o;
}

// ---------------- W[K][N] fp32 -> Wt[N][K] bf16 (tiled transpose) ----------------
__global__ __launch_bounds__(256) void transpose_convert(const float* __restrict__ W,
                                                         u16* __restrict__ Wt,
                                                         int K, int N) {
  __shared__ float tile[32][33];
  const int n0 = blockIdx.x * 32, k0 = blockIdx.y * 32;
  const int tx = threadIdx.x & 31, ty = threadIdx.x >> 5;
#pragma unroll
  for (int r = 0; r < 32; r += 8)
    tile[ty + r][tx] = W[(size_t)(k0 + ty + r) * N + (n0 + tx)];
  __syncthreads();
#pragma unroll
  for (int r = 0; r < 32; r += 8)
    Wt[(size_t)(n0 + ty + r) * K + (k0 + tx)] = f2bf(tile[tx][ty + r]);
}

// ------- V cols of QKV[2048][6144] -> Vt[8][128][2048] bf16 (d-major) -------
__global__ __launch_bounds__(256) void transpose_v(const u16* __restrict__ Vsrc,
                                                   u16* __restrict__ Vt) {
  __shared__ u16 tile[32][33];
  const int t0 = blockIdx.x * 32, d0 = blockIdx.y * 32, hkv = blockIdx.z;
  const int tx = threadIdx.x & 31, ty = threadIdx.x >> 5;
#pragma unroll
  for (int r = 0; r < 32; r += 8)
    tile[ty + r][tx] = Vsrc[(size_t)(t0 + ty + r) * 6144 + hkv * 128 + d0 + tx];
  __syncthreads();
#pragma unroll
  for (int r = 0; r < 32; r += 8)
    Vt[((size_t)hkv * 128 + d0 + ty + r) * 2048 + t0 + tx] = tile[tx][ty + r];
}

// ---------------- RoPE cos/sin table: tab[t][d] for t<2048, d<64 ----------------
__global__ __launch_bounds__(256) void rope_table(float2* __restrict__ tab,
                                                  const int* __restrict__ pos_ptr) {
  int idx = blockIdx.x * 256 + threadIdx.x;  // 131072
  int d = idx & 63, t = idx >> 6;
  int pos = *pos_ptr;
  float inv = exp2f(-(float)d * (0.015625f * 18.931568569324174f));
  float ang = (float)(pos + t) * inv;
  tab[idx] = make_float2(cosf(ang), sinf(ang));
}

// ---------------- RoPE apply in-place on bf16 [T][stride] ----------------
__global__ __launch_bounds__(256) void rope_apply(u16* __restrict__ X, int nheads,
                                                  int stride,
                                                  const float2* __restrict__ tab) {
  int idx = blockIdx.x * 256 + threadIdx.x;
  int total = 2048 * nheads * 64;
  if (idx >= total) return;
  int d = idx & 63;
  int h = (idx >> 6) % nheads;
  int t = idx / (64 * nheads);
  float2 cs = tab[t * 64 + d];
  size_t base = (size_t)t * stride + h * 128 + d;
  float x1 = bf2f(X[base]);
  float x2 = bf2f(X[base + 64]);
  X[base]      = f2bf(x1 * cs.x - x2 * cs.y);
  X[base + 64] = f2bf(x2 * cs.x + x1 * cs.y);
}

// ---------------- bf16 GEMM: C[M][N] = A[M][K] @ Bt[N][K]^T ----------------
template <int OUT_BF16>
__global__ __launch_bounds__(256) void gemm_bt(const u16* __restrict__ A,
                                               const u16* __restrict__ Bt,
                                               void* __restrict__ C,
                                               int M, int N, int K) {
  __shared__ alignas(16) u16 As[128 * 32];
  __shared__ alignas(16) u16 Bs[128 * 32];
  const int tid = threadIdx.x;
  const int w = tid >> 6, lane = tid & 63;
  const int l15 = lane & 15, lg = lane >> 4;
  const int wr = w >> 1, wc = w & 1;
  const int m0 = blockIdx.y * 128, n0 = blockIdx.x * 128;
  const int srow = lane >> 2;
  const int scol = (lane & 3) * 8;

  f32x4 acc[4][4];
#pragma unroll
  for (int i = 0; i < 4; ++i)
#pragma unroll
    for (int j = 0; j < 4; ++j) {
      f32x4 z = {0.f, 0.f, 0.f, 0.f};
      acc[i][j] = z;
    }

  for (int k0 = 0; k0 < K; k0 += 32) {
#pragma unroll
    for (int p = 0; p < 2; ++p) {
      const int rbase = w * 32 + p * 16;
      GLD16(A  + (size_t)(m0 + rbase + srow) * K + k0 + scol, &As[rbase * 32]);
      GLD16(Bt + (size_t)(n0 + rbase + srow) * K + k0 + scol, &Bs[rbase * 32]);
    }
    __syncthreads();
    bf16x8 af[4], bfr[4];
#pragma unroll
    for (int i = 0; i < 4; ++i)
      af[i] = *reinterpret_cast<const bf16x8*>(&As[(wr * 64 + i * 16 + l15) * 32 + lg * 8]);
#pragma unroll
    for (int j = 0; j < 4; ++j)
      bfr[j] = *reinterpret_cast<const bf16x8*>(&Bs[(wc * 64 + j * 16 + l15) * 32 + lg * 8]);
#pragma unroll
    for (int i = 0; i < 4; ++i)
#pragma unroll
      for (int j = 0; j < 4; ++j)
        acc[i][j] = __builtin_amdgcn_mfma_f32_16x16x32_bf16(af[i], bfr[j], acc[i][j], 0, 0, 0);
    __syncthreads();
  }

#pragma unroll
  for (int i = 0; i < 4; ++i)
#pragma unroll
    for (int j = 0; j < 4; ++j)
#pragma unroll
      for (int r = 0; r < 4; ++r) {
        const int row = m0 + wr * 64 + i * 16 + lg * 4 + r;
        const int col = n0 + wc * 64 + j * 16 + l15;
        const float v = acc[i][j][r];
        if (OUT_BF16) ((u16*)C)[(size_t)row * N + col] = f2bf(v);
        else          ((float*)C)[(size_t)row * N + col] = v;
      }
}

// ---------------- GQA causal flash attention ----------------
// grid (16, 32) = (q-blocks reversed, heads). QBLK=128: 4 waves x 32 q-rows
// (2 fragments each). KVBLK=64, double-buffered swizzled LDS, 1 barrier/tile.
__global__ __launch_bounds__(256) void attn_kernel(const u16* __restrict__ Q,
                                                   const u16* __restrict__ K,
                                                   const u16* __restrict__ Vt,
                                                   u16* __restrict__ O,
                                                   const int* __restrict__ pos_ptr) {
  const int pos = *pos_ptr;
  const int h = blockIdx.y;
  const int hkv = h >> 2;
  const int tid = threadIdx.x;
  const int w = tid >> 6, lane = tid & 63;
  const int l15 = lane & 15, lg = lane >> 4;

  __shared__ alignas(16) u16 Ks[2][64 * 128];  // K tile [64][128], swizzled
  __shared__ alignas(16) u16 Vs[2][128 * 64];  // V^T tile [128][64], swizzled
  __shared__ alignas(16) u16 Pl[4][16][72];    // per-wave P staging: 64 wide + pad

  const int qb = (int)gridDim.x - 1 - (int)blockIdx.x;  // heavy blocks first
  const int qt0 = qb * 128;
  const int nst = 2 * qb + 2;

  const u16* Kh = K + hkv * 128;                 // row stride 6144
  const u16* Vh = Vt + (size_t)hkv * 128 * 2048; // row stride 2048

  bf16x8 qa[2][4];
#pragma unroll
  for (int f = 0; f < 2; ++f) {
    const int qrow = qt0 + w * 32 + f * 16 + l15;
#pragma unroll
    for (int kk = 0; kk < 4; ++kk)
      qa[f][kk] = *reinterpret_cast<const bf16x8*>(
          Q + (size_t)qrow * 6144 + h * 128 + kk * 32 + lg * 8);
  }

  f32x4 acc[2][8];
#pragma unroll
  for (int f = 0; f < 2; ++f)
#pragma unroll
    for (int i = 0; i < 8; ++i) { f32x4 z = {0.f, 0.f, 0.f, 0.f}; acc[f][i] = z; }
  float mrun[2][4], lrun[2][4];
#pragma unroll
  for (int f = 0; f < 2; ++f)
#pragma unroll
    for (int r = 0; r < 4; ++r) {
      mrun[f][r] = (pos > 0) ? 0.0f : -INFINITY;  // zero-key prefix: logit 0 x pos
      lrun[f][r] = (float)pos;
    }

  const float scale = 0.08838834764831845f;  // 1/sqrt(128)
  const int wvb = tid & ~63;

#define STAGE_TILE(st_, b_)                                                        \
  do {                                                                             \
    const int s0_ = (st_) * 64;                                                    \
    _Pragma("unroll")                                                              \
    for (int p = 0; p < 4; ++p) {                                                  \
      const int idx = p * 256 + tid;                                               \
      const int kr = idx >> 4, kc = (idx & 15) ^ (kr & 7);                         \
      GLD16(Kh + (size_t)(s0_ + kr) * 6144 + kc * 8, &Ks[b_][(p * 256 + wvb) * 8]);\
      const int vr = idx >> 3, vc = (idx & 7) ^ (vr & 7);                          \
      GLD16(Vh + (size_t)vr * 2048 + s0_ + vc * 8, &Vs[b_][(p * 256 + wvb) * 8]);  \
    }                                                                              \
  } while (0)

  STAGE_TILE(0, 0);
  __syncthreads();
  int cur = 0;

  for (int st = 0; st < nst; ++st) {
    if (st + 1 < nst) STAGE_TILE(st + 1, cur ^ 1);
    const int s0 = st * 64;

#pragma unroll
    for (int f = 0; f < 2; ++f) {
      const int frag_base = qt0 + w * 32 + f * 16;

      // ---- QK^T: four 16x16 s-subtiles from swizzled K LDS ----
      float pv[4][4];
      __builtin_amdgcn_s_setprio(1);
#pragma unroll
      for (int sub = 0; sub < 4; ++sub) {
        f32x4 s4 = {0.f, 0.f, 0.f, 0.f};
        const int row = sub * 16 + l15;
#pragma unroll
        for (int kk = 0; kk < 4; ++kk) {
          const int chunk = (kk * 4 + lg) ^ (row & 7);
          bf16x8 kf = *reinterpret_cast<const bf16x8*>(&Ks[cur][row * 128 + chunk * 8]);
          s4 = __builtin_amdgcn_mfma_f32_16x16x32_bf16(qa[f][kk], kf, s4, 0, 0, 0);
        }
#pragma unroll
        for (int r = 0; r < 4; ++r) pv[sub][r] = s4[r];
      }
      __builtin_amdgcn_s_setprio(0);

      // ---- online softmax ----
      const bool maskt = (s0 + 64 > frag_base);
      float sf[4];
#pragma unroll
      for (int r = 0; r < 4; ++r) {
        const int qrow = frag_base + lg * 4 + r;
        float mx = -INFINITY;
#pragma unroll
        for (int sub = 0; sub < 4; ++sub) {
          float v = pv[sub][r] * scale;
          if (maskt) {
            const int scol = s0 + sub * 16 + l15;
            v = (scol <= qrow) ? v : -INFINITY;
          }
          pv[sub][r] = v;
          mx = fmaxf(mx, v);
        }
#pragma unroll
        for (int off = 1; off < 16; off <<= 1) mx = fmaxf(mx, __shfl_xor(mx, off));
        const float mnew = fmaxf(mrun[f][r], mx);
        const float scf = __expf(mrun[f][r] - mnew);
        sf[r] = scf;
        float psum = 0.0f;
#pragma unroll
        for (int sub = 0; sub < 4; ++sub) {
          const float p = __expf(pv[sub][r] - mnew);
          pv[sub][r] = p;
          psum += p;
        }
#pragma unroll
        for (int off = 1; off < 16; off <<= 1) psum += __shfl_xor(psum, off);
        lrun[f][r] = lrun[f][r] * scf + psum;
        mrun[f][r] = mnew;
      }
#pragma unroll
      for (int dc = 0; dc < 8; ++dc)
#pragma unroll
        for (int r = 0; r < 4; ++r) acc[f][dc][r] *= sf[r];

      // ---- P -> per-wave LDS (wave-local, no barrier) ----
#pragma unroll
      for (int sub = 0; sub < 4; ++sub)
#pragma unroll
        for (int r = 0; r < 4; ++r)
          Pl[w][lg * 4 + r][sub * 16 + l15] = f2bf(pv[sub][r]);

      // ---- PV: acc[16q][128d] += P[16][64] @ V[64][128] ----
      __builtin_amdgcn_s_setprio(1);
#pragma unroll
      for (int ks = 0; ks < 2; ++ks) {
        bf16x8 pf = *reinterpret_cast<const bf16x8*>(&Pl[w][l15][ks * 32 + lg * 8]);
#pragma unroll
        for (int dc = 0; dc < 8; ++dc) {
          const int row = dc * 16 + l15;
          const int chunk = (ks * 4 + lg) ^ (row & 7);
          bf16x8 vf = *reinterpret_cast<const bf16x8*>(&Vs[cur][row * 64 + chunk * 8]);
          acc[f][dc] = __builtin_amdgcn_mfma_f32_16x16x32_bf16(pf, vf, acc[f][dc], 0, 0, 0);
        }
      }
      __builtin_amdgcn_s_setprio(0);
    }

    __syncthreads();  // next tile staged + buffer swap safe
    cur ^= 1;
  }
#undef STAGE_TILE

#pragma unroll
  for (int f = 0; f < 2; ++f)
#pragma unroll
    for (int dc = 0; dc < 8; ++dc)
#pragma unroll
      for (int r = 0; r < 4; ++r) {
        const int qrow = qt0 + w * 32 + f * 16 + lg * 4 + r;
        O[(size_t)qrow * 4096 + h * 128 + dc * 16 + l15] = f2bf(acc[f][dc][r] / lrun[f][r]);
      }
}

extern "C" void kernel_launch(void* const* d_in, const int* in_sizes, int n_in,
                              void* d_out, int out_size, void* d_ws, size_t ws_size,
                              hipStream_t stream) {
  const float* hs = (const float*)d_in[0];
  const float* Wq = (const float*)d_in[1];
  const float* Wk = (const float*)d_in[2];
  const float* Wv = (const float*)d_in[3];
  const float* Wo = (const float*)d_in[4];
  const int* pos  = (const int*)d_in[5];

  char* ws = (char*)d_ws;
  // layout (88 MB total):
  u16* hs_bf = (u16*)(ws + 0);            // [2048][4096] bf16 (16 MB)
  u16* WT    = (u16*)(ws + 16777216ULL);  // [6144][4096] bf16 (48 MB): Wq|Wk|Wv rows
  u16* QKVb  = (u16*)(ws + 67108864ULL);  // [2048][6144] bf16 (24 MB)
  // aliases of dead regions (valid after QKV GEMM):
  u16* attnO = hs_bf;                          // [2048][4096] (16 MB), hs_bf dead
  u16* WoT   = WT;                             // [4096][4096] (32 MB), WqT rows dead
  u16* Vtg   = (u16*)(ws + 50331648ULL);       // [8][128][2048] (4 MB), WkT rows dead
  float2* tabF = (float2*)(ws + 54525952ULL);  // [2048][64] (1 MB), WvT rows dead

  f32_to_bf16<<<8192, 256, 0, stream>>>(hs, hs_bf, 2097152);
  transpose_convert<<<dim3(128, 128), 256, 0, stream>>>(Wq, WT, 4096, 4096);
  transpose_convert<<<dim3(32, 128), 256, 0, stream>>>(Wk, WT + (size_t)4096 * 4096, 4096, 1024);
  transpose_convert<<<dim3(32, 128), 256, 0, stream>>>(Wv, WT + (size_t)5120 * 4096, 4096, 1024);

  // fused QKV projection: C = hs_bf @ WT^T -> [2048][6144]
  gemm_bt<1><<<dim3(48, 16), 256, 0, stream>>>(hs_bf, WT, QKVb, 2048, 6144, 4096);

  // Wo transpose AFTER QKV GEMM (WoT overwrites dead WqT rows)
  transpose_convert<<<dim3(128, 128), 256, 0, stream>>>(Wo, WoT, 4096, 4096);

  rope_table<<<512, 256, 0, stream>>>(tabF, pos);
  rope_apply<<<16384, 256, 0, stream>>>(QKVb, 32, 6144, tabF);        // Q cols
  rope_apply<<<4096, 256, 0, stream>>>(QKVb + 4096, 8, 6144, tabF);   // K cols

  // V cols -> Vt[hkv][d][t]
  transpose_v<<<dim3(64, 4, 8), 256, 0, stream>>>(QKVb + 5120, Vtg);

  attn_kernel<<<dim3(16, 32), 256, 0, stream>>>(QKVb, QKVb + 4096, Vtg, attnO, pos);

  gemm_bt<0><<<dim3(32, 16), 256, 0, stream>>>(attnO, WoT, d_out, 2048, 4096, 4096);
}

// Round 6
// 430.375 us; speedup vs baseline: 2.4527x; 1.1036x over previous
//
#include <hip/hip_runtime.h>
#include <hip/hip_bf16.h>
#include <math.h>

typedef unsigned short u16;
typedef __attribute__((ext_vector_type(4))) float f32x4;
typedef __attribute__((ext_vector_type(8))) short bf16x8;

#define GLD16(gptr, lptr) __builtin_amdgcn_global_load_lds( \
    (const __attribute__((address_space(1))) void*)(gptr),  \
    (__attribute__((address_space(3))) void*)(lptr), 16, 0, 0)

__device__ __forceinline__ float bf2f(u16 u) {
  union { unsigned int i; float f; } c; c.i = ((unsigned int)u) << 16; return c.f;
}
__device__ __forceinline__ u16 f2bf(float f) {
  union { float f; unsigned int i; } c; c.f = f;
  unsigned int r = c.i + 0x7fffu + ((c.i >> 16) & 1u);
  return (u16)(r >> 16);
}

// ---------------- fp32 -> bf16 elementwise (float4 vectorized) ----------------
__global__ __launch_bounds__(256) void f32_to_bf16(const float* __restrict__ in,
                                                   u16* __restrict__ out, int n4) {
  int i = blockIdx.x * 256 + threadIdx.x;
  if (i >= n4) return;
  float4 v = reinterpret_cast<const float4*>(in)[i];
  ushort4 o;
  o.x = f2bf(v.x); o.y = f2bf(v.y); o.z = f2bf(v.z); o.w = f2bf(v.w);
  reinterpret_cast<ushort4*>(out)[i] = o;
}

// ---------------- W[K][N] fp32 -> Wt[N][K] bf16 (tiled transpose) ----------------
__global__ __launch_bounds__(256) void transpose_convert(const float* __restrict__ W,
                                                         u16* __restrict__ Wt,
                                                         int K, int N) {
  __shared__ float tile[32][33];
  const int n0 = blockIdx.x * 32, k0 = blockIdx.y * 32;
  const int tx = threadIdx.x & 31, ty = threadIdx.x >> 5;
#pragma unroll
  for (int r = 0; r < 32; r += 8)
    tile[ty + r][tx] = W[(size_t)(k0 + ty + r) * N + (n0 + tx)];
  __syncthreads();
#pragma unroll
  for (int r = 0; r < 32; r += 8)
    Wt[(size_t)(n0 + ty + r) * K + (k0 + tx)] = f2bf(tile[tx][ty + r]);
}

// ------- V cols of QKV[2048][6144] -> Vt[8][128][2048] bf16 (d-major) -------
__global__ __launch_bounds__(256) void transpose_v(const u16* __restrict__ Vsrc,
                                                   u16* __restrict__ Vt) {
  __shared__ u16 tile[32][33];
  const int t0 = blockIdx.x * 32, d0 = blockIdx.y * 32, hkv = blockIdx.z;
  const int tx = threadIdx.x & 31, ty = threadIdx.x >> 5;
#pragma unroll
  for (int r = 0; r < 32; r += 8)
    tile[ty + r][tx] = Vsrc[(size_t)(t0 + ty + r) * 6144 + hkv * 128 + d0 + tx];
  __syncthreads();
#pragma unroll
  for (int r = 0; r < 32; r += 8)
    Vt[((size_t)hkv * 128 + d0 + ty + r) * 2048 + t0 + tx] = tile[tx][ty + r];
}

// ---------------- RoPE cos/sin table: tab[t][d] for t<2048, d<64 ----------------
__global__ __launch_bounds__(256) void rope_table(float2* __restrict__ tab,
                                                  const int* __restrict__ pos_ptr) {
  int idx = blockIdx.x * 256 + threadIdx.x;  // 131072
  int d = idx & 63, t = idx >> 6;
  int pos = *pos_ptr;
  float inv = exp2f(-(float)d * (0.015625f * 18.931568569324174f));
  float ang = (float)(pos + t) * inv;
  tab[idx] = make_float2(cosf(ang), sinf(ang));
}

// ---------------- RoPE apply in-place on bf16 [T][stride] ----------------
__global__ __launch_bounds__(256) void rope_apply(u16* __restrict__ X, int nheads,
                                                  int stride,
                                                  const float2* __restrict__ tab) {
  int idx = blockIdx.x * 256 + threadIdx.x;
  int total = 2048 * nheads * 64;
  if (idx >= total) return;
  int d = idx & 63;
  int h = (idx >> 6) % nheads;
  int t = idx / (64 * nheads);
  float2 cs = tab[t * 64 + d];
  size_t base = (size_t)t * stride + h * 128 + d;
  float x1 = bf2f(X[base]);
  float x2 = bf2f(X[base + 64]);
  X[base]      = f2bf(x1 * cs.x - x2 * cs.y);
  X[base + 64] = f2bf(x2 * cs.x + x1 * cs.y);
}

// ---------------- bf16 GEMM: C[M][N] = A[M][K] @ Bt[N][K]^T ----------------
template <int OUT_BF16>
__global__ __launch_bounds__(256) void gemm_bt(const u16* __restrict__ A,
                                               const u16* __restrict__ Bt,
                                               void* __restrict__ C,
                                               int M, int N, int K) {
  __shared__ alignas(16) u16 As[128 * 32];
  __shared__ alignas(16) u16 Bs[128 * 32];
  const int tid = threadIdx.x;
  const int w = tid >> 6, lane = tid & 63;
  const int l15 = lane & 15, lg = lane >> 4;
  const int wr = w >> 1, wc = w & 1;
  const int m0 = blockIdx.y * 128, n0 = blockIdx.x * 128;
  const int srow = lane >> 2;
  const int scol = (lane & 3) * 8;

  f32x4 acc[4][4];
#pragma unroll
  for (int i = 0; i < 4; ++i)
#pragma unroll
    for (int j = 0; j < 4; ++j) {
      f32x4 z = {0.f, 0.f, 0.f, 0.f};
      acc[i][j] = z;
    }

  for (int k0 = 0; k0 < K; k0 += 32) {
#pragma unroll
    for (int p = 0; p < 2; ++p) {
      const int rbase = w * 32 + p * 16;
      GLD16(A  + (size_t)(m0 + rbase + srow) * K + k0 + scol, &As[rbase * 32]);
      GLD16(Bt + (size_t)(n0 + rbase + srow) * K + k0 + scol, &Bs[rbase * 32]);
    }
    __syncthreads();
    bf16x8 af[4], bfr[4];
#pragma unroll
    for (int i = 0; i < 4; ++i)
      af[i] = *reinterpret_cast<const bf16x8*>(&As[(wr * 64 + i * 16 + l15) * 32 + lg * 8]);
#pragma unroll
    for (int j = 0; j < 4; ++j)
      bfr[j] = *reinterpret_cast<const bf16x8*>(&Bs[(wc * 64 + j * 16 + l15) * 32 + lg * 8]);
#pragma unroll
    for (int i = 0; i < 4; ++i)
#pragma unroll
      for (int j = 0; j < 4; ++j)
        acc[i][j] = __builtin_amdgcn_mfma_f32_16x16x32_bf16(af[i], bfr[j], acc[i][j], 0, 0, 0);
    __syncthreads();
  }

#pragma unroll
  for (int i = 0; i < 4; ++i)
#pragma unroll
    for (int j = 0; j < 4; ++j)
#pragma unroll
      for (int r = 0; r < 4; ++r) {
        const int row = m0 + wr * 64 + i * 16 + lg * 4 + r;
        const int col = n0 + wc * 64 + j * 16 + l15;
        const float v = acc[i][j][r];
        if (OUT_BF16) ((u16*)C)[(size_t)row * N + col] = f2bf(v);
        else          ((float*)C)[(size_t)row * N + col] = v;
      }
}

// ---------------- GQA causal flash attention ----------------
// grid (8, 32): block bx handles q-tiles (8+bx) then (7-bx) -> exactly 34
// KV-tile computes per block (perfect balance), 256 blocks = 1/CU.
// 4 waves x 32 q-rows. KVBLK=64, dbuf swizzled LDS, 1 barrier/tile.
// Softmax in raw-logit space: p = exp2(fma(s, C, -m*C)), C = scale*log2(e).
// Defer-max (T13): rescale only when a lane-local max exceeds m+THR (__all test,
// no shuffles in common path). Row-sum kept as per-lane partials, reduced once.
__global__ __launch_bounds__(256) void attn_kernel(const u16* __restrict__ Q,
                                                   const u16* __restrict__ K,
                                                   const u16* __restrict__ Vt,
                                                   u16* __restrict__ O,
                                                   const int* __restrict__ pos_ptr) {
  const int pos = *pos_ptr;
  const int h = blockIdx.y;
  const int hkv = h >> 2;
  const int tid = threadIdx.x;
  const int w = tid >> 6, lane = tid & 63;
  const int l15 = lane & 15, lg = lane >> 4;

  __shared__ alignas(16) u16 Ks[2][64 * 128];  // K tile [64][128], swizzled
  __shared__ alignas(16) u16 Vs[2][128 * 64];  // V^T tile [128][64], swizzled
  __shared__ alignas(16) u16 Pl[4][16][72];    // per-wave P staging

  const u16* Kh = K + hkv * 128;                 // row stride 6144
  const u16* Vh = Vt + (size_t)hkv * 128 * 2048; // row stride 2048

  const float C = 0.12752961957823275f;  // (1/sqrt(128)) * log2(e)
  const float THR = 62.0f;               // raw defer-max threshold (exp2 arg <= ~7.9)
  const int wvb = tid & ~63;

#define STAGE_TILE(st_, b_)                                                        \
  do {                                                                             \
    const int s0_ = (st_) * 64;                                                    \
    _Pragma("unroll")                                                              \
    for (int p = 0; p < 4; ++p) {                                                  \
      const int idx = p * 256 + tid;                                               \
      const int kr = idx >> 4, kc = (idx & 15) ^ (kr & 7);                         \
      GLD16(Kh + (size_t)(s0_ + kr) * 6144 + kc * 8, &Ks[b_][(p * 256 + wvb) * 8]);\
      const int vr = idx >> 3, vc = (idx & 7) ^ (vr & 7);                          \
      GLD16(Vh + (size_t)vr * 2048 + s0_ + vc * 8, &Vs[b_][(p * 256 + wvb) * 8]);  \
    }                                                                              \
  } while (0)

  for (int pass = 0; pass < 2; ++pass) {
    const int qb = (pass == 0) ? (8 + (int)blockIdx.x) : (7 - (int)blockIdx.x);
    const int qt0 = qb * 128;
    const int nst = 2 * qb + 2;

    bf16x8 qa[2][4];
#pragma unroll
    for (int f = 0; f < 2; ++f) {
      const int qrow = qt0 + w * 32 + f * 16 + l15;
#pragma unroll
      for (int kk = 0; kk < 4; ++kk)
        qa[f][kk] = *reinterpret_cast<const bf16x8*>(
            Q + (size_t)qrow * 6144 + h * 128 + kk * 32 + lg * 8);
    }

    f32x4 acc[2][8];
#pragma unroll
    for (int f = 0; f < 2; ++f)
#pragma unroll
      for (int i = 0; i < 8; ++i) { f32x4 z = {0.f, 0.f, 0.f, 0.f}; acc[f][i] = z; }
    float mrun[2][4], lpart[2][4];
#pragma unroll
    for (int f = 0; f < 2; ++f)
#pragma unroll
      for (int r = 0; r < 4; ++r) {
        mrun[f][r] = (pos > 0) ? 0.0f : -INFINITY;  // zero-key prefix logit = 0 (raw)
        lpart[f][r] = 0.0f;
      }

    STAGE_TILE(0, 0);
    __syncthreads();
    int cur = 0;

    for (int st = 0; st < nst; ++st) {
      if (st + 1 < nst) STAGE_TILE(st + 1, cur ^ 1);
      const int s0 = st * 64;

#pragma unroll
      for (int f = 0; f < 2; ++f) {
        const int frag_base = qt0 + w * 32 + f * 16;

        // ---- QK^T (raw logits): four 16x16 s-subtiles from swizzled K LDS ----
        float pv[4][4];
        __builtin_amdgcn_s_setprio(1);
#pragma unroll
        for (int sub = 0; sub < 4; ++sub) {
          f32x4 s4 = {0.f, 0.f, 0.f, 0.f};
          const int row = sub * 16 + l15;
#pragma unroll
          for (int kk = 0; kk < 4; ++kk) {
            const int chunk = (kk * 4 + lg) ^ (row & 7);
            bf16x8 kf = *reinterpret_cast<const bf16x8*>(&Ks[cur][row * 128 + chunk * 8]);
            s4 = __builtin_amdgcn_mfma_f32_16x16x32_bf16(qa[f][kk], kf, s4, 0, 0, 0);
          }
#pragma unroll
          for (int r = 0; r < 4; ++r) pv[sub][r] = s4[r];
        }
        __builtin_amdgcn_s_setprio(0);

        // ---- causal mask (raw space), diagonal tiles only ----
        if (s0 + 64 > frag_base) {
#pragma unroll
          for (int r = 0; r < 4; ++r) {
            const int qrow = frag_base + lg * 4 + r;
#pragma unroll
            for (int sub = 0; sub < 4; ++sub) {
              const int scol = s0 + sub * 16 + l15;
              pv[sub][r] = (scol <= qrow) ? pv[sub][r] : -INFINITY;
            }
          }
        }

        // ---- defer-max: lane-local maxima, wave-uniform rescale decision ----
        float lmax[4];
#pragma unroll
        for (int r = 0; r < 4; ++r)
          lmax[r] = fmaxf(fmaxf(pv[0][r], pv[1][r]), fmaxf(pv[2][r], pv[3][r]));
        float dml = fmaxf(fmaxf(lmax[0] - mrun[f][0], lmax[1] - mrun[f][1]),
                          fmaxf(lmax[2] - mrun[f][2], lmax[3] - mrun[f][3]));
        if (!__all(dml <= THR)) {
          float sfr[4];
#pragma unroll
          for (int r = 0; r < 4; ++r) {
            float mx = lmax[r];
#pragma unroll
            for (int off = 1; off < 16; off <<= 1) mx = fmaxf(mx, __shfl_xor(mx, off));
            const float mnew = fmaxf(mrun[f][r], mx);
            sfr[r] = exp2f((mrun[f][r] - mnew) * C);
            mrun[f][r] = mnew;
            lpart[f][r] *= sfr[r];
          }
#pragma unroll
          for (int dc = 0; dc < 8; ++dc)
#pragma unroll
            for (int r = 0; r < 4; ++r) acc[f][dc][r] *= sfr[r];
        }

        // ---- P = exp2(fma(s, C, -m*C)), per-lane partial row-sums ----
#pragma unroll
        for (int r = 0; r < 4; ++r) {
          const float nmC = -mrun[f][r] * C;
          float ps = 0.0f;
#pragma unroll
          for (int sub = 0; sub < 4; ++sub) {
            const float p = exp2f(fmaf(pv[sub][r], C, nmC));
            pv[sub][r] = p;
            ps += p;
          }
          lpart[f][r] += ps;
        }

        // ---- P -> per-wave LDS (wave-local, no barrier) ----
#pragma unroll
        for (int sub = 0; sub < 4; ++sub)
#pragma unroll
          for (int r = 0; r < 4; ++r)
            Pl[w][lg * 4 + r][sub * 16 + l15] = f2bf(pv[sub][r]);

        // ---- PV: acc[16q][128d] += P[16][64] @ V[64][128] ----
        __builtin_amdgcn_s_setprio(1);
#pragma unroll
        for (int ks = 0; ks < 2; ++ks) {
          bf16x8 pf = *reinterpret_cast<const bf16x8*>(&Pl[w][l15][ks * 32 + lg * 8]);
#pragma unroll
          for (int dc = 0; dc < 8; ++dc) {
            const int row = dc * 16 + l15;
            const int chunk = (ks * 4 + lg) ^ (row & 7);
            bf16x8 vf = *reinterpret_cast<const bf16x8*>(&Vs[cur][row * 64 + chunk * 8]);
            acc[f][dc] = __builtin_amdgcn_mfma_f32_16x16x32_bf16(pf, vf, acc[f][dc], 0, 0, 0);
          }
        }
        __builtin_amdgcn_s_setprio(0);
      }

      __syncthreads();  // next tile staged + buffer swap safe
      cur ^= 1;
    }

    // ---- epilogue: final l reduction (once per q-tile) + output ----
#pragma unroll
    for (int f = 0; f < 2; ++f)
#pragma unroll
      for (int r = 0; r < 4; ++r) {
        float l = lpart[f][r];
#pragma unroll
        for (int off = 1; off < 16; off <<= 1) l += __shfl_xor(l, off);
        if (pos > 0) l += (float)pos * exp2f(-mrun[f][r] * C);  // zero-key prefix
        const float linv = 1.0f / l;
        const int qrow = qt0 + w * 32 + f * 16 + lg * 4 + r;
#pragma unroll
        for (int dc = 0; dc < 8; ++dc)
          O[(size_t)qrow * 4096 + h * 128 + dc * 16 + l15] = f2bf(acc[f][dc][r] * linv);
      }
  }
#undef STAGE_TILE
}

extern "C" void kernel_launch(void* const* d_in, const int* in_sizes, int n_in,
                              void* d_out, int out_size, void* d_ws, size_t ws_size,
                              hipStream_t stream) {
  const float* hs = (const float*)d_in[0];
  const float* Wq = (const float*)d_in[1];
  const float* Wk = (const float*)d_in[2];
  const float* Wv = (const float*)d_in[3];
  const float* Wo = (const float*)d_in[4];
  const int* pos  = (const int*)d_in[5];

  char* ws = (char*)d_ws;
  // layout (88 MB total):
  u16* hs_bf = (u16*)(ws + 0);            // [2048][4096] bf16 (16 MB)
  u16* WT    = (u16*)(ws + 16777216ULL);  // [6144][4096] bf16 (48 MB): Wq|Wk|Wv rows
  u16* QKVb  = (u16*)(ws + 67108864ULL);  // [2048][6144] bf16 (24 MB)
  // aliases of dead regions (valid after QKV GEMM):
  u16* attnO = hs_bf;                          // [2048][4096] (16 MB), hs_bf dead
  u16* WoT   = WT;                             // [4096][4096] (32 MB), WqT rows dead
  u16* Vtg   = (u16*)(ws + 50331648ULL);       // [8][128][2048] (4 MB), WkT rows dead
  float2* tabF = (float2*)(ws + 54525952ULL);  // [2048][64] (1 MB), WvT rows dead

  f32_to_bf16<<<8192, 256, 0, stream>>>(hs, hs_bf, 2097152);
  transpose_convert<<<dim3(128, 128), 256, 0, stream>>>(Wq, WT, 4096, 4096);
  transpose_convert<<<dim3(32, 128), 256, 0, stream>>>(Wk, WT + (size_t)4096 * 4096, 4096, 1024);
  transpose_convert<<<dim3(32, 128), 256, 0, stream>>>(Wv, WT + (size_t)5120 * 4096, 4096, 1024);

  // fused QKV projection: C = hs_bf @ WT^T -> [2048][6144]
  gemm_bt<1><<<dim3(48, 16), 256, 0, stream>>>(hs_bf, WT, QKVb, 2048, 6144, 4096);

  // Wo transpose AFTER QKV GEMM (WoT overwrites dead WqT rows)
  transpose_convert<<<dim3(128, 128), 256, 0, stream>>>(Wo, WoT, 4096, 4096);

  rope_table<<<512, 256, 0, stream>>>(tabF, pos);
  rope_apply<<<16384, 256, 0, stream>>>(QKVb, 32, 6144, tabF);        // Q cols
  rope_apply<<<4096, 256, 0, stream>>>(QKVb + 4096, 8, 6144, tabF);   // K cols

  // V cols -> Vt[hkv][d][t]
  transpose_v<<<dim3(64, 4, 8), 256, 0, stream>>>(QKVb + 5120, Vtg);

  attn_kernel<<<dim3(8, 32), 256, 0, stream>>>(QKVb, QKVb + 4096, Vtg, attnO, pos);

  gemm_bt<0><<<dim3(32, 16), 256, 0, stream>>>(attnO, WoT, d_out, 2048, 4096, 4096);
}